// Round 1
// baseline (1268.720 us; speedup 1.0000x reference)
//
#include <hip/hip_runtime.h>
#include <math.h>

#define HIDDEN 128
#define MUL1   64
#define ACOLS  320   // HIDDEN + 3*MUL1
#define TBINS  4096
#define EB     32    // edges per block-chunk

// ---------------- K1: tabulate R_n(x) over [0,5] ----------------
__global__ __launch_bounds__(128) void build_table(const float* __restrict__ W1,
                                                   const float* __restrict__ W2,
                                                   float* __restrict__ T) {
  __shared__ float hsh[64];
  const int i = blockIdx.x;        // 0..TBINS
  const int tid = threadIdx.x;     // 0..127
  const float x = (float)i * (5.0f / TBINS);
  if (tid < 64) {
    const bool valid = (x > 0.0f) && (x < 5.0f);
    const float invx = valid ? (1.0f / x) : 0.0f;   // invx=0 zeroes rad -> z=0 -> h=0
    float z = 0.0f;
#pragma unroll
    for (int r = 0; r < 8; ++r) {
      float arg = (float)(r + 1) * 0.6283185307f * x;     // k*pi*x/5
      float rad = 0.6324555320f * sinf(arg) * invx;       // sqrt(2/5)*sin/x
      z += rad * (W1[r * 64 + tid] * 0.3535533906f);      // W1/sqrt(8)
    }
    float sg = 1.0f / (1.0f + expf(-z));
    hsh[tid] = 1.679177f * z * sg;                        // SILU_2MOM * silu
  }
  __syncthreads();
  float acc = 0.0f;
  for (int j = 0; j < 64; ++j)
    acc += hsh[j] * W2[j * HIDDEN + tid];
  T[(size_t)i * HIDDEN + tid] = acc * 0.125f;             // W2/8
}

// ---------------- K2: edge kernel (gather, nf scatter, Wtp1 GEMM, f1 scatter) ----
__global__ __launch_bounds__(256) void edge_kernel(
    const float* __restrict__ attrs, const int* __restrict__ eidx,
    const float* __restrict__ evec,  const float* __restrict__ elen,
    const float* __restrict__ Wtp1,  const float* __restrict__ T,
    float* __restrict__ out, int n_edges, int n_chunks)
{
  __shared__ float Wlt[MUL1][132];       // Wtp1 transposed [m][k], padded (33.8KB)
  __shared__ float nf_l[EB][HIDDEN];     // 16KB
  __shared__ float y1_l[EB][3];
  __shared__ float w0_l[EB], w1_l[EB];
  __shared__ int   i0_l[EB], s_l[EB], r_l[EB];
  const int tid = threadIdx.x;

  for (int idx = tid; idx < HIDDEN * MUL1; idx += 256)
    Wlt[idx & 63][idx >> 6] = Wtp1[idx];   // [k][m] -> [m][k]

  for (int ch = blockIdx.x; ch < n_chunks; ch += gridDim.x) {
    const int base = ch * EB;
    __syncthreads();                        // protect LDS reuse + Wlt staging
    if (tid < EB) {
      const int e = base + tid;
      const bool ok = e < n_edges;
      int s = ok ? eidx[e] : 0;
      int r = ok ? eidx[n_edges + e] : 0;
      float x = ok ? elen[e] : 1.0f;
      float v0 = ok ? evec[e * 3 + 0] : 0.0f;
      float v1 = ok ? evec[e * 3 + 1] : 0.0f;
      float v2 = ok ? evec[e * 3 + 2] : 0.0f;
      float rn = rsqrtf(v0 * v0 + v1 * v1 + v2 * v2);
      if (!ok) rn = 0.0f;
      y1_l[tid][0] = 1.7320508076f * v1 * rn;   // unit[:, [1,2,0]] * sqrt3
      y1_l[tid][1] = 1.7320508076f * v2 * rn;
      y1_l[tid][2] = 1.7320508076f * v0 * rn;
      float u = x * ((float)TBINS / 5.0f);
      int i0 = (int)floorf(u);
      i0 = i0 < 0 ? 0 : (i0 > TBINS - 1 ? TBINS - 1 : i0);
      float fr = u - (float)i0;
      const bool valid = ok && (x > 0.0f) && (x < 5.0f);
      w0_l[tid] = valid ? (1.0f - fr) : 0.0f;
      w1_l[tid] = valid ? fr : 0.0f;
      i0_l[tid] = i0; s_l[tid] = s; r_l[tid] = r;
    }
    __syncthreads();
    // ---- P1: nf = attrs[sender] * lerp(R_n table); scatter S; stash nf in LDS
    {
      const int k = tid & 127;
      const int eg = tid >> 7;              // 2 groups x 16 edges
      for (int ee = 0; ee < 16; ++ee) {
        const int le = eg * 16 + ee;
        const int i0 = i0_l[le];
        float R = w0_l[le] * T[(size_t)i0 * HIDDEN + k]
                + w1_l[le] * T[(size_t)(i0 + 1) * HIDDEN + k];
        float a = attrs[(size_t)s_l[le] * HIDDEN + k];
        float nf = a * R;
        nf_l[le][k] = nf;
        atomicAdd(&out[(size_t)r_l[le] * ACOLS + k], nf);
      }
    }
    __syncthreads();
    // ---- P2: t = nf @ Wtp1; scatter f1 = t*inv (x) Y1
    {
      const int m = tid & 63;
      const int eg2 = tid >> 6;             // 4 groups x 8 edges
      float acc[8];
#pragma unroll
      for (int ee = 0; ee < 8; ++ee) acc[ee] = 0.0f;
      const float4* wrow = (const float4*)&Wlt[m][0];
      for (int q = 0; q < 32; ++q) {
        const float4 w4 = wrow[q];
#pragma unroll
        for (int ee = 0; ee < 8; ++ee) {
          const float4 n4 = *(const float4*)&nf_l[eg2 * 8 + ee][q * 4];
          acc[ee] += n4.x * w4.x + n4.y * w4.y + n4.z * w4.z + n4.w * w4.w;
        }
      }
      const float inv = 0.0883883476f;      // 1/sqrt(128)
#pragma unroll
      for (int ee = 0; ee < 8; ++ee) {
        const int le = eg2 * 8 + ee;
        const float t = acc[ee] * inv;
        const size_t rb = (size_t)r_l[le] * ACOLS + HIDDEN + m * 3;
        atomicAdd(&out[rb + 0], t * y1_l[le][0]);
        atomicAdd(&out[rb + 1], t * y1_l[le][1]);
        atomicAdd(&out[rb + 2], t * y1_l[le][2]);
      }
    }
  }
}

// ---------------- K3: A0 = S @ Wtp0 * inv, in place on out[:, :128] -------------
__global__ __launch_bounds__(256) void node_wtp0(const float* __restrict__ Wtp0,
                                                 float* __restrict__ out, int n_nodes) {
  __shared__ float S[64][HIDDEN];     // 32KB
  __shared__ float Wqt[HIDDEN][36];   // 18KB, transposed quarter [k][j], padded
  const int tid = threadIdx.x;
  const int nb = blockIdx.x * 64;
  for (int idx = tid; idx < 64 * HIDDEN; idx += 256) {
    const int nn = idx >> 7, kk = idx & 127;
    const int n = nb + nn;
    S[nn][kk] = (n < n_nodes) ? out[(size_t)n * ACOLS + kk] : 0.0f;
  }
  const int k = tid & 127;
  const int g = tid >> 7;             // 2 groups x 32 nodes
  float acc[32];
#pragma unroll
  for (int i = 0; i < 32; ++i) acc[i] = 0.0f;
  for (int q = 0; q < 4; ++q) {
    __syncthreads();
    for (int idx = tid; idx < 32 * HIDDEN; idx += 256) {
      const int j = idx >> 7, kk = idx & 127;
      Wqt[kk][j] = Wtp0[(q * 32 + j) * HIDDEN + kk];
    }
    __syncthreads();
    const float4* wr = (const float4*)&Wqt[k][0];
    for (int j4 = 0; j4 < 8; ++j4) {
      const float4 w4 = wr[j4];
#pragma unroll
      for (int nn = 0; nn < 32; ++nn) {
        const float4 s4 = *(const float4*)&S[g * 32 + nn][q * 32 + j4 * 4];
        acc[nn] += s4.x * w4.x + s4.y * w4.y + s4.z * w4.z + s4.w * w4.w;
      }
    }
  }
  const float inv = 0.0883883476f;    // 1/sqrt(128)
  const int gbase = nb + g * 32;
  for (int nn = 0; nn < 32; ++nn) {
    const int n = gbase + nn;
    if (n < n_nodes) out[(size_t)n * ACOLS + k] = acc[nn] * inv;
  }
}

// ---------------- K4: B0 = [A0^2, sum(A1^2)/sqrt3]; out[:, :128] += B0 @ Wmix ----
__global__ __launch_bounds__(256) void node_mix(const float* __restrict__ Wmix,
                                                float* __restrict__ out, int n_nodes) {
  __shared__ float B0[64][192];       // 48KB
  __shared__ float Wct[HIDDEN][20];   // 10KB, transposed chunk [k][j], padded
  const int tid = threadIdx.x;
  const int nb = blockIdx.x * 64;
  for (int idx = tid; idx < 64 * 192; idx += 256) {
    const int nn = idx / 192, c = idx % 192;
    const int n = nb + nn;
    float v = 0.0f;
    if (n < n_nodes) {
      const float* row = out + (size_t)n * ACOLS;
      if (c < 128) { const float a = row[c]; v = a * a; }
      else {
        const int m = c - 128;
        const float a0 = row[128 + m * 3 + 0];
        const float a1 = row[128 + m * 3 + 1];
        const float a2 = row[128 + m * 3 + 2];
        v = (a0 * a0 + a1 * a1 + a2 * a2) * 0.5773502692f;  // 1/sqrt(3)
      }
    }
    B0[nn][c] = v;
  }
  const int k = tid & 127;
  const int g = tid >> 7;
  float acc[32];
#pragma unroll
  for (int i = 0; i < 32; ++i) acc[i] = 0.0f;
  for (int cch = 0; cch < 12; ++cch) {
    __syncthreads();
    for (int idx = tid; idx < 16 * HIDDEN; idx += 256) {
      const int j = idx >> 7, kk = idx & 127;
      Wct[kk][j] = Wmix[(cch * 16 + j) * HIDDEN + kk];
    }
    __syncthreads();
    const float4* wr = (const float4*)&Wct[k][0];
    for (int j4 = 0; j4 < 4; ++j4) {
      const float4 w4 = wr[j4];
#pragma unroll
      for (int nn = 0; nn < 32; ++nn) {
        const float4 b4 = *(const float4*)&B0[g * 32 + nn][cch * 16 + j4 * 4];
        acc[nn] += b4.x * w4.x + b4.y * w4.y + b4.z * w4.z + b4.w * w4.w;
      }
    }
  }
  const float invm = 0.0721687836f;   // 1/sqrt(192)
  for (int nn = 0; nn < 32; ++nn) {
    const int n = nb + g * 32 + nn;
    if (n < n_nodes) {
      const size_t o = (size_t)n * ACOLS + k;
      out[o] += acc[nn] * invm;
    }
  }
}

extern "C" void kernel_launch(void* const* d_in, const int* in_sizes, int n_in,
                              void* d_out, int out_size, void* d_ws, size_t ws_size,
                              hipStream_t stream) {
  const float* attrs = (const float*)d_in[0];
  const int*   eidx  = (const int*)d_in[1];
  const float* evec  = (const float*)d_in[2];
  const float* elen  = (const float*)d_in[3];
  const float* W1    = (const float*)d_in[4];
  const float* W2    = (const float*)d_in[5];
  const float* Wtp0  = (const float*)d_in[6];
  const float* Wtp1  = (const float*)d_in[7];
  const float* Wmix  = (const float*)d_in[8];
  float* out = (float*)d_out;
  float* T   = (float*)d_ws;          // (TBINS+1) x 128 floats = 2.1 MB

  const int n_nodes = in_sizes[0] / HIDDEN;
  const int n_edges = in_sizes[1] / 2;

  hipMemsetAsync(d_out, 0, (size_t)out_size * sizeof(float), stream);
  build_table<<<TBINS + 1, 128, 0, stream>>>(W1, W2, T);
  const int n_chunks = (n_edges + EB - 1) / EB;
  edge_kernel<<<768, 256, 0, stream>>>(attrs, eidx, evec, elen, Wtp1, T, out,
                                       n_edges, n_chunks);
  const int nb = (n_nodes + 63) / 64;
  node_wtp0<<<nb, 256, 0, stream>>>(Wtp0, out, n_nodes);
  node_mix<<<nb, 256, 0, stream>>>(Wmix, out, n_nodes);
}

// Round 2
// 799.264 us; speedup vs baseline: 1.5874x; 1.5874x over previous
//
#include <hip/hip_runtime.h>
#include <math.h>

#define HIDDEN 128
#define MUL1   64
#define ACOLS  320   // HIDDEN + 3*MUL1
#define TBINS  4096

__device__ __forceinline__ float rlane(float v, int k) {
  return __int_as_float(__builtin_amdgcn_readlane(__float_as_int(v), k));
}

// ---------------- K1: tabulate R_n(x) over [0,5] ----------------
__global__ __launch_bounds__(128) void build_table(const float* __restrict__ W1,
                                                   const float* __restrict__ W2,
                                                   float* __restrict__ T) {
  __shared__ float hsh[64];
  const int i = blockIdx.x;        // 0..TBINS
  const int tid = threadIdx.x;     // 0..127
  const float x = (float)i * (5.0f / TBINS);
  if (tid < 64) {
    const bool valid = (x > 0.0f) && (x < 5.0f);
    const float invx = valid ? (1.0f / x) : 0.0f;
    float z = 0.0f;
#pragma unroll
    for (int r = 0; r < 8; ++r) {
      float arg = (float)(r + 1) * 0.6283185307f * x;     // k*pi*x/5
      float rad = 0.6324555320f * sinf(arg) * invx;       // sqrt(2/5)*sin/x
      z += rad * (W1[r * 64 + tid] * 0.3535533906f);      // W1/sqrt(8)
    }
    float sg = 1.0f / (1.0f + expf(-z));
    hsh[tid] = 1.679177f * z * sg;
  }
  __syncthreads();
  float acc = 0.0f;
  for (int j = 0; j < 64; ++j)
    acc += hsh[j] * W2[j * HIDDEN + tid];
  T[(size_t)i * HIDDEN + tid] = acc * 0.125f;             // W2/8
}

// ---------------- K2: histogram receivers ----------------
__global__ void hist_kernel(const int* __restrict__ recv, int* __restrict__ cnt,
                            int n_edges) {
  const int i = blockIdx.x * blockDim.x + threadIdx.x;
  if (i < n_edges) atomicAdd(&cnt[recv[i]], 1);
}

// ---------------- K3: single-block exclusive scan -> off, cur ----------------
__global__ __launch_bounds__(1024) void scan_kernel(const int* __restrict__ cnt,
                                                    int* __restrict__ off,
                                                    int* __restrict__ cur, int n) {
  __shared__ int sums[1024];
  const int t = threadIdx.x;
  const int chunk = (n + 1023) >> 10;
  const int beg = t * chunk;
  const int end = min(beg + chunk, n);
  int s = 0;
  for (int i = beg; i < end; ++i) s += cnt[i];
  sums[t] = s;
  __syncthreads();
  for (int d = 1; d < 1024; d <<= 1) {
    int x = sums[t];
    int y = (t >= d) ? sums[t - d] : 0;
    __syncthreads();
    sums[t] = x + y;
    __syncthreads();
  }
  int run = (t == 0) ? 0 : sums[t - 1];
  for (int i = beg; i < end; ++i) { off[i] = run; cur[i] = run; run += cnt[i]; }
  if (t == 1023) off[n] = sums[1023];
}

// ---------------- K4: build sorted 32B edge records ----------------
// rec = {s, w0, w1, i0, y0, y1, y2, pad} at position atomicAdd(cur[r])
__global__ void scatter_kernel(const int* __restrict__ eidx,
                               const float* __restrict__ evec,
                               const float* __restrict__ elen,
                               int* __restrict__ cur, float4* __restrict__ recs,
                               int n_edges) {
  const int e = blockIdx.x * blockDim.x + threadIdx.x;
  if (e >= n_edges) return;
  const int s = eidx[e], r = eidx[n_edges + e];
  const float x = elen[e];
  const float v0 = evec[3 * e], v1 = evec[3 * e + 1], v2 = evec[3 * e + 2];
  const float rn = rsqrtf(v0 * v0 + v1 * v1 + v2 * v2);
  const float u = x * ((float)TBINS / 5.0f);
  int i0 = (int)floorf(u);
  i0 = i0 < 0 ? 0 : (i0 > TBINS - 1 ? TBINS - 1 : i0);
  const float fr = u - (float)i0;
  const bool valid = (x > 0.0f) && (x < 5.0f);
  const float w0 = valid ? 1.0f - fr : 0.0f;
  const float w1 = valid ? fr : 0.0f;
  const int pos = atomicAdd(&cur[r], 1);
  recs[2 * pos]     = make_float4(__int_as_float(s), w0, w1, __int_as_float(i0));
  recs[2 * pos + 1] = make_float4(1.7320508076f * v1 * rn,   // unit[:, [1,2,0]]*sqrt3
                                  1.7320508076f * v2 * rn,
                                  1.7320508076f * v0 * rn, 0.0f);
}

// ---------------- K5: wave-per-node gather + Wtp1 GEMM + Wtp0 GEMM ----------------
// Writes the ENTIRE out row (A0 = S@Wtp0*inv in cols 0..127, A1 in 128..319).
__global__ __launch_bounds__(1024) void node_gather(
    const float* __restrict__ attrs, const float* __restrict__ Wtp0,
    const float* __restrict__ Wtp1, const float* __restrict__ T,
    const float4* __restrict__ recs, const int* __restrict__ off,
    float* __restrict__ out, int n_nodes) {
  __shared__ float Wt0[HIDDEN * HIDDEN];   // 64KB, natural [k][j]
  __shared__ float Wt1[HIDDEN * MUL1];     // 32KB, natural [k][m]
  for (int i = threadIdx.x; i < HIDDEN * HIDDEN; i += 1024) Wt0[i] = Wtp0[i];
  for (int i = threadIdx.x; i < HIDDEN * MUL1; i += 1024) Wt1[i] = Wtp1[i];
  __syncthreads();
  const int lane = threadIdx.x & 63;
  const int wid = (blockIdx.x << 4) + (threadIdx.x >> 6);
  const int nw = gridDim.x << 4;
  const float inv = 0.0883883476f;         // 1/sqrt(128)
  for (int n = wid; n < n_nodes; n += nw) {
    const int beg = off[n], end = off[n + 1];
    float S0 = 0.f, S1 = 0.f, ax = 0.f, ay = 0.f, az = 0.f;
    for (int i = beg; i < end; i += 4) {
      float nfl[4], nfh[4], yy0[4], yy1[4], yy2[4];
#pragma unroll
      for (int b = 0; b < 4; ++b) {
        const bool ok = (i + b) < end;
        const int idx = ok ? (i + b) : beg;       // clamp; zeroed via w0=w1=0
        const float4 ra = recs[2 * idx];
        const float4 rb = recs[2 * idx + 1];
        const int s = __float_as_int(ra.x);
        const float w0 = ok ? ra.y : 0.f;
        const float w1 = ok ? ra.z : 0.f;
        const int i0 = __float_as_int(ra.w);
        const float* Trow = T + (size_t)i0 * HIDDEN;
        const float Rl = w0 * Trow[lane]      + w1 * Trow[HIDDEN + lane];
        const float Rh = w0 * Trow[64 + lane] + w1 * Trow[HIDDEN + 64 + lane];
        const float* arow = attrs + (size_t)s * HIDDEN;
        const float l = arow[lane] * Rl;
        const float h = arow[64 + lane] * Rh;
        nfl[b] = l; nfh[b] = h; S0 += l; S1 += h;
        yy0[b] = rb.x; yy1[b] = rb.y; yy2[b] = rb.z;
      }
      // t_m = sum_k nf_k * Wtp1[k][m], m = lane; 4 edges share the k-loop
      float t0 = 0.f, t1 = 0.f, t2 = 0.f, t3 = 0.f;
#pragma unroll 8
      for (int k = 0; k < 64; ++k) {
        const float wlo = Wt1[k * MUL1 + lane];
        const float whi = Wt1[(64 + k) * MUL1 + lane];
        t0 += rlane(nfl[0], k) * wlo + rlane(nfh[0], k) * whi;
        t1 += rlane(nfl[1], k) * wlo + rlane(nfh[1], k) * whi;
        t2 += rlane(nfl[2], k) * wlo + rlane(nfh[2], k) * whi;
        t3 += rlane(nfl[3], k) * wlo + rlane(nfh[3], k) * whi;
      }
      ax += t0 * yy0[0] + t1 * yy0[1] + t2 * yy0[2] + t3 * yy0[3];
      ay += t0 * yy1[0] + t1 * yy1[1] + t2 * yy1[2] + t3 * yy1[3];
      az += t0 * yy2[0] + t1 * yy2[1] + t2 * yy2[2] + t3 * yy2[3];
    }
    // A0[j] = sum_k S_k * Wtp0[k][j] * inv; lane j covers j and j+64
    float A0l = 0.f, A0h = 0.f;
#pragma unroll 8
    for (int k = 0; k < 64; ++k) {
      const float slo = rlane(S0, k), shi = rlane(S1, k);
      A0l += slo * Wt0[k * HIDDEN + lane]      + shi * Wt0[(64 + k) * HIDDEN + lane];
      A0h += slo * Wt0[k * HIDDEN + 64 + lane] + shi * Wt0[(64 + k) * HIDDEN + 64 + lane];
    }
    float* orow = out + (size_t)n * ACOLS;
    orow[lane] = A0l * inv;
    orow[64 + lane] = A0h * inv;
    orow[HIDDEN + 3 * lane + 0] = ax * inv;
    orow[HIDDEN + 3 * lane + 1] = ay * inv;
    orow[HIDDEN + 3 * lane + 2] = az * inv;
  }
}

// ---------------- K6: wave-per-2-nodes B0 @ Wmix, added in place ----------------
__global__ __launch_bounds__(1024) void node_mix2(const float* __restrict__ Wmix,
                                                  float* __restrict__ out,
                                                  int n_nodes) {
  __shared__ float Wm[192 * HIDDEN];       // 96KB, natural [c][j]
  for (int i = threadIdx.x; i < 192 * HIDDEN; i += 1024) Wm[i] = Wmix[i];
  __syncthreads();
  const int lane = threadIdx.x & 63;
  const int wid = (blockIdx.x << 4) + (threadIdx.x >> 6);
  const int nw = gridDim.x << 4;
  const float invm = 0.0721687836f;        // 1/sqrt(192)
  const float is3 = 0.5773502692f;         // 1/sqrt(3)
  for (int p = wid * 2; p < n_nodes; p += nw * 2) {
    const bool has1 = (p + 1) < n_nodes;
    float* r0 = out + (size_t)p * ACOLS;
    float* r1 = has1 ? out + (size_t)(p + 1) * ACOLS : r0;
    // B0 distributed: lane c holds B0[c], B0[64+c], B0[128+c]
    const float a0 = r0[lane], b0 = r0[64 + lane];
    const float q0 = r0[HIDDEN + 3 * lane], q1 = r0[HIDDEN + 3 * lane + 1],
                q2 = r0[HIDDEN + 3 * lane + 2];
    const float B0a = a0 * a0, B0b = b0 * b0,
                B0c = (q0 * q0 + q1 * q1 + q2 * q2) * is3;
    const float a1 = r1[lane], b1 = r1[64 + lane];
    const float s0 = r1[HIDDEN + 3 * lane], s1 = r1[HIDDEN + 3 * lane + 1],
                s2 = r1[HIDDEN + 3 * lane + 2];
    const float B1a = a1 * a1, B1b = b1 * b1,
                B1c = (s0 * s0 + s1 * s1 + s2 * s2) * is3;
    float m00 = 0.f, m01 = 0.f, m10 = 0.f, m11 = 0.f;  // node0/node1, cols 2l,2l+1
#pragma unroll 8
    for (int c = 0; c < 64; ++c) {
      const float2 w = *(const float2*)&Wm[c * HIDDEN + 2 * lane];
      const float x0 = rlane(B0a, c), x1 = rlane(B1a, c);
      m00 += x0 * w.x; m01 += x0 * w.y; m10 += x1 * w.x; m11 += x1 * w.y;
    }
#pragma unroll 8
    for (int c = 0; c < 64; ++c) {
      const float2 w = *(const float2*)&Wm[(64 + c) * HIDDEN + 2 * lane];
      const float x0 = rlane(B0b, c), x1 = rlane(B1b, c);
      m00 += x0 * w.x; m01 += x0 * w.y; m10 += x1 * w.x; m11 += x1 * w.y;
    }
#pragma unroll 8
    for (int c = 0; c < 64; ++c) {
      const float2 w = *(const float2*)&Wm[(128 + c) * HIDDEN + 2 * lane];
      const float x0 = rlane(B0c, c), x1 = rlane(B1c, c);
      m00 += x0 * w.x; m01 += x0 * w.y; m10 += x1 * w.x; m11 += x1 * w.y;
    }
    float2 o0 = *(float2*)&r0[2 * lane];
    o0.x += m00 * invm; o0.y += m01 * invm;
    *(float2*)&r0[2 * lane] = o0;
    if (has1) {
      float2 o1 = *(float2*)&r1[2 * lane];
      o1.x += m10 * invm; o1.y += m11 * invm;
      *(float2*)&r1[2 * lane] = o1;
    }
  }
}

extern "C" void kernel_launch(void* const* d_in, const int* in_sizes, int n_in,
                              void* d_out, int out_size, void* d_ws, size_t ws_size,
                              hipStream_t stream) {
  const float* attrs = (const float*)d_in[0];
  const int*   eidx  = (const int*)d_in[1];
  const float* evec  = (const float*)d_in[2];
  const float* elen  = (const float*)d_in[3];
  const float* W1    = (const float*)d_in[4];
  const float* W2    = (const float*)d_in[5];
  const float* Wtp0  = (const float*)d_in[6];
  const float* Wtp1  = (const float*)d_in[7];
  const float* Wmix  = (const float*)d_in[8];
  float* out = (float*)d_out;

  const int n_nodes = in_sizes[0] / HIDDEN;
  const int n_edges = in_sizes[1] / 2;

  // workspace layout: recs (32B*E) | T | cnt | off | cur   (~15.5 MB)
  char* ws = (char*)d_ws;
  float4* recs = (float4*)ws;
  size_t o1 = (size_t)n_edges * 32;
  float* T = (float*)(ws + o1);
  size_t o2 = o1 + (size_t)(TBINS + 1) * HIDDEN * 4;
  int* cnt = (int*)(ws + o2);
  size_t o3 = o2 + (size_t)n_nodes * 4;
  int* off = (int*)(ws + o3);
  size_t o4 = o3 + (size_t)(n_nodes + 1) * 4;
  int* cur = (int*)(ws + o4);

  hipMemsetAsync(cnt, 0, (size_t)n_nodes * 4, stream);
  build_table<<<TBINS + 1, 128, 0, stream>>>(W1, W2, T);
  hist_kernel<<<(n_edges + 255) / 256, 256, 0, stream>>>(eidx + n_edges, cnt, n_edges);
  scan_kernel<<<1, 1024, 0, stream>>>(cnt, off, cur, n_nodes);
  scatter_kernel<<<(n_edges + 255) / 256, 256, 0, stream>>>(eidx, evec, elen, cur,
                                                            recs, n_edges);
  node_gather<<<256, 1024, 0, stream>>>(attrs, Wtp0, Wtp1, T, recs, off, out, n_nodes);
  node_mix2<<<256, 1024, 0, stream>>>(Wmix, out, n_nodes);
}

// Round 3
// 530.991 us; speedup vs baseline: 2.3893x; 1.5052x over previous
//
#include <hip/hip_runtime.h>
#include <math.h>

#define HIDDEN 128
#define MUL1   64
#define ACOLS  320   // HIDDEN + 3*MUL1
#define TBINS  4096

__device__ __forceinline__ float rlane(float v, int k) {
  return __int_as_float(__builtin_amdgcn_readlane(__float_as_int(v), k));
}

// ---------------- K1: fused R_n table build (interleaved pairs) + receiver histogram
// Tq[(i*128+k)*2 + c] = T[i+c][k]  -> one b128 gives both lerp rows for 2 channels.
__global__ __launch_bounds__(128) void tab_hist(const float* __restrict__ W1,
                                                const float* __restrict__ W2,
                                                float* __restrict__ Tq,
                                                const int* __restrict__ recv,
                                                int* __restrict__ cnt, int n_edges) {
  const int tid = threadIdx.x;
  if (blockIdx.x > TBINS) {   // histogram blocks
    const int e = (blockIdx.x - (TBINS + 1)) * 128 + tid;
    if (e < n_edges) atomicAdd(&cnt[recv[e]], 1);
    return;
  }
  __shared__ float hsh[64];
  const int i = blockIdx.x;        // 0..TBINS
  const float x = (float)i * (5.0f / TBINS);
  if (tid < 64) {
    const bool valid = (x > 0.0f) && (x < 5.0f);
    const float invx = valid ? (1.0f / x) : 0.0f;
    float z = 0.0f;
#pragma unroll
    for (int r = 0; r < 8; ++r) {
      float arg = (float)(r + 1) * 0.6283185307f * x;     // k*pi*x/5
      float rad = 0.6324555320f * sinf(arg) * invx;       // sqrt(2/5)*sin/x
      z += rad * (W1[r * 64 + tid] * 0.3535533906f);      // W1/sqrt(8)
    }
    float sg = 1.0f / (1.0f + expf(-z));
    hsh[tid] = 1.679177f * z * sg;
  }
  __syncthreads();
  float acc = 0.0f;
  for (int j = 0; j < 64; ++j)
    acc += hsh[j] * W2[j * HIDDEN + tid];
  acc *= 0.125f;                                          // W2/8
  Tq[((size_t)i * HIDDEN + tid) * 2] = acc;               // row i as c=0
  if (i >= 1)
    Tq[((size_t)(i - 1) * HIDDEN + tid) * 2 + 1] = acc;   // row i as c=1 of i-1
}

// ---------------- K2: single-block exclusive scan -> off, cur ----------------
__global__ __launch_bounds__(1024) void scan_kernel(const int* __restrict__ cnt,
                                                    int* __restrict__ off,
                                                    int* __restrict__ cur, int n) {
  __shared__ int sums[1024];
  const int t = threadIdx.x;
  const int chunk = (n + 1023) >> 10;
  const int beg = t * chunk;
  const int end = min(beg + chunk, n);
  int s = 0;
  for (int i = beg; i < end; ++i) s += cnt[i];
  sums[t] = s;
  __syncthreads();
  for (int d = 1; d < 1024; d <<= 1) {
    int x = sums[t];
    int y = (t >= d) ? sums[t - d] : 0;
    __syncthreads();
    sums[t] = x + y;
    __syncthreads();
  }
  int run = (t == 0) ? 0 : sums[t - 1];
  for (int i = beg; i < end; ++i) { off[i] = run; cur[i] = run; run += cnt[i]; }
  if (t == 1023) off[n] = sums[1023];
}

// ---------------- K3: build sorted 32B edge records ----------------
__global__ void scatter_kernel(const int* __restrict__ eidx,
                               const float* __restrict__ evec,
                               const float* __restrict__ elen,
                               int* __restrict__ cur, float4* __restrict__ recs,
                               int n_edges) {
  const int e = blockIdx.x * blockDim.x + threadIdx.x;
  if (e >= n_edges) return;
  const int s = eidx[e], r = eidx[n_edges + e];
  const float x = elen[e];
  const float v0 = evec[3 * e], v1 = evec[3 * e + 1], v2 = evec[3 * e + 2];
  const float rn = rsqrtf(v0 * v0 + v1 * v1 + v2 * v2);
  const float u = x * ((float)TBINS / 5.0f);
  int i0 = (int)floorf(u);
  i0 = i0 < 0 ? 0 : (i0 > TBINS - 1 ? TBINS - 1 : i0);
  const float fr = u - (float)i0;
  const bool valid = (x > 0.0f) && (x < 5.0f);
  const float w0 = valid ? 1.0f - fr : 0.0f;
  const float w1 = valid ? fr : 0.0f;
  const int pos = atomicAdd(&cur[r], 1);
  recs[2 * pos]     = make_float4(__int_as_float(s), w0, w1, __int_as_float(i0));
  recs[2 * pos + 1] = make_float4(1.7320508076f * v1 * rn,   // unit[:, [1,2,0]]*sqrt3
                                  1.7320508076f * v2 * rn,
                                  1.7320508076f * v0 * rn, 0.0f);
}

// ---------------- K4: wave-per-node: gather G,S outer-products; contract epilogues
// lane l owns channels 2l, 2l+1. G[k][d] = sum_e nf[k]*Y1[d] lives in 6 regs/lane.
__global__ __launch_bounds__(1024) void node_gather(
    const float* __restrict__ attrs, const float* __restrict__ Wtp0,
    const float* __restrict__ Wtp1, const float* __restrict__ Tq,
    const float4* __restrict__ recs, const int* __restrict__ off,
    float* __restrict__ out, int n_nodes) {
  __shared__ float Wt0i[64 * 64 * 4];   // 64KB: [(kk*64+j)*4] = W0[2kk][2j],[2kk][2j+1],[2kk+1][2j],[2kk+1][2j+1]
  __shared__ float Wt1i[64 * 64 * 2];   // 32KB: [(kk*64+m)*2] = W1[2kk][m],[2kk+1][m]
  for (int idx = threadIdx.x; idx < 4096; idx += 1024) {
    const int kk = idx >> 6, j = idx & 63;
    float4 w;
    w.x = Wtp0[(2 * kk) * HIDDEN + 2 * j];
    w.y = Wtp0[(2 * kk) * HIDDEN + 2 * j + 1];
    w.z = Wtp0[(2 * kk + 1) * HIDDEN + 2 * j];
    w.w = Wtp0[(2 * kk + 1) * HIDDEN + 2 * j + 1];
    *(float4*)&Wt0i[idx * 4] = w;
    float2 w1;
    w1.x = Wtp1[(2 * kk) * MUL1 + j];
    w1.y = Wtp1[(2 * kk + 1) * MUL1 + j];
    *(float2*)&Wt1i[idx * 2] = w1;
  }
  __syncthreads();
  const int lane = threadIdx.x & 63;
  const int wid = (blockIdx.x << 4) + (threadIdx.x >> 6);
  const int nw = gridDim.x << 4;
  const float2* attrs2 = (const float2*)attrs;
  const float inv = 0.0883883476f;       // 1/sqrt(128)
  for (int n = wid; n < n_nodes; n += nw) {
    const int beg = off[n], end = off[n + 1];
    float Sa = 0.f, Sb = 0.f;
    float Ga0 = 0.f, Ga1 = 0.f, Ga2 = 0.f, Gb0 = 0.f, Gb1 = 0.f, Gb2 = 0.f;
    for (int i = beg; i < end; i += 2) {
#pragma unroll
      for (int b = 0; b < 2; ++b) {
        const bool ok = (i + b) < end;
        const int idx = ok ? (i + b) : beg;       // clamp; zeroed via weights
        const float4 ra = recs[2 * idx];
        const float4 rb = recs[2 * idx + 1];
        const int s = __float_as_int(ra.x);
        const float w0 = ok ? ra.y : 0.f;
        const float w1v = ok ? ra.z : 0.f;
        const int i0 = __float_as_int(ra.w);
        const float4 tq = *(const float4*)&Tq[((size_t)i0 * HIDDEN + 2 * lane) * 2];
        const float2 av = attrs2[(size_t)s * 64 + lane];
        const float Ra = w0 * tq.x + w1v * tq.y;  // lerp ch 2l
        const float Rb = w0 * tq.z + w1v * tq.w;  // lerp ch 2l+1
        const float la = av.x * Ra, lb = av.y * Rb;
        Sa += la; Sb += lb;
        Ga0 += la * rb.x; Ga1 += la * rb.y; Ga2 += la * rb.z;
        Gb0 += lb * rb.x; Gb1 += lb * rb.y; Gb2 += lb * rb.z;
      }
    }
    // ---- A1[m][d] = inv * sum_k Wtp1[k][m] * G[k][d], m = lane
    float a1x = 0.f, a1y = 0.f, a1z = 0.f;
#pragma unroll 8
    for (int kk = 0; kk < 64; ++kk) {
      const float2 w = *(const float2*)&Wt1i[(kk * 64 + lane) * 2];
      a1x += rlane(Ga0, kk) * w.x + rlane(Gb0, kk) * w.y;
      a1y += rlane(Ga1, kk) * w.x + rlane(Gb1, kk) * w.y;
      a1z += rlane(Ga2, kk) * w.x + rlane(Gb2, kk) * w.y;
    }
    // ---- A0[2j],[2j+1] = inv * sum_k S[k] * Wtp0[k][2j+c], j = lane
    float A0x = 0.f, A0y = 0.f;
#pragma unroll 8
    for (int kk = 0; kk < 64; ++kk) {
      const float4 w = *(const float4*)&Wt0i[(kk * 64 + lane) * 4];
      const float sa = rlane(Sa, kk), sb = rlane(Sb, kk);
      A0x += sa * w.x + sb * w.z;
      A0y += sa * w.y + sb * w.w;
    }
    float* orow = out + (size_t)n * ACOLS;
    *(float2*)&orow[2 * lane] = make_float2(A0x * inv, A0y * inv);
    orow[HIDDEN + 3 * lane + 0] = a1x * inv;
    orow[HIDDEN + 3 * lane + 1] = a1y * inv;
    orow[HIDDEN + 3 * lane + 2] = a1z * inv;
  }
}

// ---------------- K5: wave-per-2-nodes B0 @ Wmix, added in place ----------------
__global__ __launch_bounds__(1024) void node_mix2(const float* __restrict__ Wmix,
                                                  float* __restrict__ out,
                                                  int n_nodes) {
  __shared__ float Wm[192 * HIDDEN];       // 96KB, natural [c][j]
  for (int i = threadIdx.x; i < 192 * HIDDEN; i += 1024) Wm[i] = Wmix[i];
  __syncthreads();
  const int lane = threadIdx.x & 63;
  const int wid = (blockIdx.x << 4) + (threadIdx.x >> 6);
  const int nw = gridDim.x << 4;
  const float invm = 0.0721687836f;        // 1/sqrt(192)
  const float is3 = 0.5773502692f;         // 1/sqrt(3)
  for (int p = wid * 2; p < n_nodes; p += nw * 2) {
    const bool has1 = (p + 1) < n_nodes;
    float* r0 = out + (size_t)p * ACOLS;
    float* r1 = has1 ? out + (size_t)(p + 1) * ACOLS : r0;
    const float a0 = r0[lane], b0 = r0[64 + lane];
    const float q0 = r0[HIDDEN + 3 * lane], q1 = r0[HIDDEN + 3 * lane + 1],
                q2 = r0[HIDDEN + 3 * lane + 2];
    const float B0a = a0 * a0, B0b = b0 * b0,
                B0c = (q0 * q0 + q1 * q1 + q2 * q2) * is3;
    const float a1 = r1[lane], b1 = r1[64 + lane];
    const float s0 = r1[HIDDEN + 3 * lane], s1 = r1[HIDDEN + 3 * lane + 1],
                s2 = r1[HIDDEN + 3 * lane + 2];
    const float B1a = a1 * a1, B1b = b1 * b1,
                B1c = (s0 * s0 + s1 * s1 + s2 * s2) * is3;
    float m00 = 0.f, m01 = 0.f, m10 = 0.f, m11 = 0.f;
#pragma unroll 8
    for (int c = 0; c < 64; ++c) {
      const float2 w = *(const float2*)&Wm[c * HIDDEN + 2 * lane];
      const float x0 = rlane(B0a, c), x1 = rlane(B1a, c);
      m00 += x0 * w.x; m01 += x0 * w.y; m10 += x1 * w.x; m11 += x1 * w.y;
    }
#pragma unroll 8
    for (int c = 0; c < 64; ++c) {
      const float2 w = *(const float2*)&Wm[(64 + c) * HIDDEN + 2 * lane];
      const float x0 = rlane(B0b, c), x1 = rlane(B1b, c);
      m00 += x0 * w.x; m01 += x0 * w.y; m10 += x1 * w.x; m11 += x1 * w.y;
    }
#pragma unroll 8
    for (int c = 0; c < 64; ++c) {
      const float2 w = *(const float2*)&Wm[(128 + c) * HIDDEN + 2 * lane];
      const float x0 = rlane(B0c, c), x1 = rlane(B1c, c);
      m00 += x0 * w.x; m01 += x0 * w.y; m10 += x1 * w.x; m11 += x1 * w.y;
    }
    float2 o0 = *(float2*)&r0[2 * lane];
    o0.x += m00 * invm; o0.y += m01 * invm;
    *(float2*)&r0[2 * lane] = o0;
    if (has1) {
      float2 o1 = *(float2*)&r1[2 * lane];
      o1.x += m10 * invm; o1.y += m11 * invm;
      *(float2*)&r1[2 * lane] = o1;
    }
  }
}

extern "C" void kernel_launch(void* const* d_in, const int* in_sizes, int n_in,
                              void* d_out, int out_size, void* d_ws, size_t ws_size,
                              hipStream_t stream) {
  const float* attrs = (const float*)d_in[0];
  const int*   eidx  = (const int*)d_in[1];
  const float* evec  = (const float*)d_in[2];
  const float* elen  = (const float*)d_in[3];
  const float* W1    = (const float*)d_in[4];
  const float* W2    = (const float*)d_in[5];
  const float* Wtp0  = (const float*)d_in[6];
  const float* Wtp1  = (const float*)d_in[7];
  const float* Wmix  = (const float*)d_in[8];
  float* out = (float*)d_out;

  const int n_nodes = in_sizes[0] / HIDDEN;
  const int n_edges = in_sizes[1] / 2;

  // workspace: recs (32B*E) | Tq | cnt | off | cur   (~17.6 MB)
  char* ws = (char*)d_ws;
  float4* recs = (float4*)ws;
  size_t o1 = (size_t)n_edges * 32;
  float* Tq = (float*)(ws + o1);
  size_t o2 = o1 + (size_t)(TBINS + 1) * HIDDEN * 2 * 4;
  int* cnt = (int*)(ws + o2);
  size_t o3 = o2 + (size_t)n_nodes * 4;
  int* off = (int*)(ws + o3);
  size_t o4 = o3 + (size_t)(n_nodes + 1) * 4;
  int* cur = (int*)(ws + o4);

  hipMemsetAsync(cnt, 0, (size_t)n_nodes * 4, stream);
  const int hist_blocks = (n_edges + 127) / 128;
  tab_hist<<<TBINS + 1 + hist_blocks, 128, 0, stream>>>(W1, W2, Tq,
                                                        eidx + n_edges, cnt, n_edges);
  scan_kernel<<<1, 1024, 0, stream>>>(cnt, off, cur, n_nodes);
  scatter_kernel<<<(n_edges + 255) / 256, 256, 0, stream>>>(eidx, evec, elen, cur,
                                                            recs, n_edges);
  node_gather<<<512, 1024, 0, stream>>>(attrs, Wtp0, Wtp1, Tq, recs, off, out, n_nodes);
  node_mix2<<<256, 1024, 0, stream>>>(Wmix, out, n_nodes);
}

// Round 5
// 400.699 us; speedup vs baseline: 3.1663x; 1.3252x over previous
//
#include <hip/hip_runtime.h>
#include <math.h>

#define HIDDEN 128
#define MUL1   64
#define ACOLS  320   // HIDDEN + 3*MUL1
#define TBINS  4096

typedef unsigned short ushort_t;
typedef __attribute__((ext_vector_type(8))) short bf16x8;
typedef __attribute__((ext_vector_type(4))) float f32x4;

__device__ __forceinline__ unsigned bf16rne(float x) {
  const unsigned u = __float_as_uint(x);
  return (u + 0x7FFFu + ((u >> 16) & 1u)) >> 16;
}
__device__ __forceinline__ unsigned pack2(float a, float b) {
  return bf16rne(a) | (bf16rne(b) << 16);
}

// ---------------- K1: fused R_n table build (interleaved pairs) + receiver histogram
__global__ __launch_bounds__(128) void tab_hist(const float* __restrict__ W1,
                                                const float* __restrict__ W2,
                                                float* __restrict__ Tq,
                                                const int* __restrict__ recv,
                                                int* __restrict__ cnt, int n_edges) {
  const int tid = threadIdx.x;
  if (blockIdx.x > TBINS) {   // histogram blocks
    const int e = (blockIdx.x - (TBINS + 1)) * 128 + tid;
    if (e < n_edges) atomicAdd(&cnt[recv[e]], 1);
    return;
  }
  __shared__ float hsh[64];
  const int i = blockIdx.x;        // 0..TBINS
  const float x = (float)i * (5.0f / TBINS);
  if (tid < 64) {
    const bool valid = (x > 0.0f) && (x < 5.0f);
    const float invx = valid ? (1.0f / x) : 0.0f;
    float z = 0.0f;
#pragma unroll
    for (int r = 0; r < 8; ++r) {
      float arg = (float)(r + 1) * 0.6283185307f * x;     // k*pi*x/5
      float rad = 0.6324555320f * sinf(arg) * invx;       // sqrt(2/5)*sin/x
      z += rad * (W1[r * 64 + tid] * 0.3535533906f);      // W1/sqrt(8)
    }
    float sg = 1.0f / (1.0f + expf(-z));
    hsh[tid] = 1.679177f * z * sg;
  }
  __syncthreads();
  float acc = 0.0f;
  for (int j = 0; j < 64; ++j)
    acc += hsh[j] * W2[j * HIDDEN + tid];
  acc *= 0.125f;                                          // W2/8
  Tq[((size_t)i * HIDDEN + tid) * 2] = acc;               // row i as c=0
  if (i >= 1)
    Tq[((size_t)(i - 1) * HIDDEN + tid) * 2 + 1] = acc;   // row i as c=1 of i-1
}

// ---------------- K2: single-block exclusive scan -> off, cur ----------------
__global__ __launch_bounds__(1024) void scan_kernel(const int* __restrict__ cnt,
                                                    int* __restrict__ off,
                                                    int* __restrict__ cur, int n) {
  __shared__ int sums[1024];
  const int t = threadIdx.x;
  const int chunk = (n + 1023) >> 10;
  const int beg = t * chunk;
  const int end = min(beg + chunk, n);
  int s = 0;
  for (int i = beg; i < end; ++i) s += cnt[i];
  sums[t] = s;
  __syncthreads();
  for (int d = 1; d < 1024; d <<= 1) {
    int x = sums[t];
    int y = (t >= d) ? sums[t - d] : 0;
    __syncthreads();
    sums[t] = x + y;
    __syncthreads();
  }
  int run = (t == 0) ? 0 : sums[t - 1];
  for (int i = beg; i < end; ++i) { off[i] = run; cur[i] = run; run += cnt[i]; }
  if (t == 1023) off[n] = sums[1023];
}

// ---------------- K3: build sorted 32B edge records ----------------
__global__ void scatter_kernel(const int* __restrict__ eidx,
                               const float* __restrict__ evec,
                               const float* __restrict__ elen,
                               int* __restrict__ cur, float4* __restrict__ recs,
                               int n_edges) {
  const int e = blockIdx.x * blockDim.x + threadIdx.x;
  if (e >= n_edges) return;
  const int s = eidx[e], r = eidx[n_edges + e];
  const float x = elen[e];
  const float v0 = evec[3 * e], v1 = evec[3 * e + 1], v2 = evec[3 * e + 2];
  const float rn = rsqrtf(v0 * v0 + v1 * v1 + v2 * v2);
  const float u = x * ((float)TBINS / 5.0f);
  int i0 = (int)floorf(u);
  i0 = i0 < 0 ? 0 : (i0 > TBINS - 1 ? TBINS - 1 : i0);
  const float fr = u - (float)i0;
  const bool valid = (x > 0.0f) && (x < 5.0f);
  const float w0 = valid ? 1.0f - fr : 0.0f;
  const float w1 = valid ? fr : 0.0f;
  const int pos = atomicAdd(&cur[r], 1);
  recs[2 * pos]     = make_float4(__int_as_float(s), w0, w1, __int_as_float(i0));
  recs[2 * pos + 1] = make_float4(1.7320508076f * v1 * rn,   // unit[:, [1,2,0]]*sqrt3
                                  1.7320508076f * v2 * rn,
                                  1.7320508076f * v0 * rn, 0.0f);
}

// ---------------- K4: pre-scale + hi/lo split weights into MFMA B-frag order ----
// P ushort layout: W0h[16384] W0l[16384] W1h[8192] W1l[8192] Wmh[24576] Wml[24576]
// frag element: P[base + ((nt*KF+q)*64 + lane)*8 + j] = W[(quad*8+j) + q*32][nt*16+col]
__global__ __launch_bounds__(256) void pack_weights(
    const float* __restrict__ W0, const float* __restrict__ W1,
    const float* __restrict__ Wm, ushort_t* __restrict__ P) {
  const int idx = blockIdx.x * 256 + threadIdx.x;     // 0..49151
  const int j = idx & 7, lane = (idx >> 3) & 63;
  const int krow = (lane >> 4) * 8 + j, col = lane & 15;
  float v; int hb, lb;
  if (idx < 16384) {
    const int tq = idx >> 9, nt = tq >> 2, q = tq & 3;
    v = W0[(krow + q * 32) * HIDDEN + nt * 16 + col] * 0.0883883476f;
    hb = idx; lb = idx + 16384;
  } else if (idx < 24576) {
    const int i2 = idx - 16384;
    const int tq = i2 >> 9, nt = tq >> 2, q = tq & 3;
    v = W1[(krow + q * 32) * MUL1 + nt * 16 + col] * 0.0883883476f;
    hb = 32768 + i2; lb = 40960 + i2;
  } else {
    const int i3 = idx - 24576;
    const int tq = i3 >> 9, nt = tq / 6, q = tq % 6;
    v = Wm[(krow + q * 32) * HIDDEN + nt * 16 + col] * 0.0721687836f;
    hb = 49152 + i3; lb = 73728 + i3;
  }
  const unsigned h = bf16rne(v);
  P[hb] = (ushort_t)h;
  P[lb] = (ushort_t)bf16rne(v - __uint_as_float(h << 16));
}

// ---------------- K5: pure gather: per node accumulate S (128) and G (128x3),
// write 1KB bf16 record. No LDS -> high occupancy for latency hiding.
__global__ __launch_bounds__(1024) void node_sg(
    const float* __restrict__ attrs, const float* __restrict__ Tq,
    const float4* __restrict__ recs, const int* __restrict__ off,
    unsigned* __restrict__ SG, int n_nodes) {
  const int lane = threadIdx.x & 63;
  const int wid = (blockIdx.x << 4) + (threadIdx.x >> 6);
  const int nw = gridDim.x << 4;
  const float2* attrs2 = (const float2*)attrs;
  for (int n = wid; n < n_nodes; n += nw) {
    const int beg = off[n], end = off[n + 1];
    float Sa = 0.f, Sb = 0.f;
    float Ga0 = 0.f, Ga1 = 0.f, Ga2 = 0.f, Gb0 = 0.f, Gb1 = 0.f, Gb2 = 0.f;
    for (int i = beg; i < end; i += 2) {
#pragma unroll
      for (int b = 0; b < 2; ++b) {
        const bool ok = (i + b) < end;
        const int idx = ok ? (i + b) : beg;       // clamp; zeroed via weights
        const float4 ra = recs[2 * idx];
        const float4 rb = recs[2 * idx + 1];
        const int s = __float_as_int(ra.x);
        const float w0 = ok ? ra.y : 0.f;
        const float w1v = ok ? ra.z : 0.f;
        const int i0 = __float_as_int(ra.w);
        const float4 tq = *(const float4*)&Tq[((size_t)i0 * HIDDEN + 2 * lane) * 2];
        const float2 av = attrs2[(size_t)s * 64 + lane];
        const float Ra = w0 * tq.x + w1v * tq.y;  // lerp ch 2l
        const float Rb = w0 * tq.z + w1v * tq.w;  // lerp ch 2l+1
        const float la = av.x * Ra, lb = av.y * Rb;
        Sa += la; Sb += lb;
        Ga0 += la * rb.x; Ga1 += la * rb.y; Ga2 += la * rb.z;
        Gb0 += lb * rb.x; Gb1 += lb * rb.y; Gb2 += lb * rb.z;
      }
    }
    unsigned* srow = SG + (size_t)n * 256;        // 256 u32 = 512 bf16 per node
    srow[lane]       = pack2(Sa, Sb);             // S[2l], S[2l+1]
    srow[64 + lane]  = pack2(Ga0, Gb0);           // G_d0
    srow[128 + lane] = pack2(Ga1, Gb1);           // G_d1
    srow[192 + lane] = pack2(Ga2, Gb2);           // G_d2
  }
}

// ---------------- K6: wave-per-16-nodes MFMA: A0=S@W0', A1=G@W1', B0, +=B0@Wm'
// mfma_f32_16x16x32_bf16: A lane: [m=lane&15][k=quad*8+j]; C/D: col=lane&15,
// row=quad*4+reg (m89-verified). Mix GEMM accumulates into A0 C-frags.
__global__ __launch_bounds__(256) void node_mfma(
    const ushort_t* __restrict__ SG, const ushort_t* __restrict__ P,
    float* __restrict__ out, int n_nodes) {
  __shared__ float B0s[4][16][196];   // per-wave B0 stage; stride 196 dw (2-way=free)
  const int lane = threadIdx.x & 63;
  const int w = threadIdx.x >> 6;
  const int tile = blockIdx.x * 4 + w;
  const int row = lane & 15, quad = lane >> 4;
  const int nA = min(tile * 16 + row, n_nodes - 1);   // clamped A-row node
  const ushort_t* sgA = SG + (size_t)nA * 512;
  const int cnode0 = tile * 16 + quad * 4;            // C-frag rows

  // ---- A0 = S @ W0' (M=16 nodes, N=128, K=128), B split hi+lo
  f32x4 c0[8];
#pragma unroll
  for (int nt = 0; nt < 8; ++nt) c0[nt] = (f32x4){0.f, 0.f, 0.f, 0.f};
  {
    bf16x8 aS[4];
#pragma unroll
    for (int q = 0; q < 4; ++q)
      aS[q] = *(const bf16x8*)(sgA + quad * 8 + q * 32);
    const ushort_t* W0h = P;
    const ushort_t* W0l = P + 16384;
#pragma unroll
    for (int nt = 0; nt < 8; ++nt)
#pragma unroll
      for (int q = 0; q < 4; ++q) {
        const int fo = ((nt * 4 + q) * 64 + lane) * 8;
        const bf16x8 bh = *(const bf16x8*)(W0h + fo);
        const bf16x8 bl = *(const bf16x8*)(W0l + fo);
        c0[nt] = __builtin_amdgcn_mfma_f32_16x16x32_bf16(aS[q], bh, c0[nt], 0, 0, 0);
        c0[nt] = __builtin_amdgcn_mfma_f32_16x16x32_bf16(aS[q], bl, c0[nt], 0, 0, 0);
      }
  }
  // ---- A1_d = G_d @ W1' (3 x [M=16, N=64, K=128])
  f32x4 c1[3][4];
#pragma unroll
  for (int d = 0; d < 3; ++d)
#pragma unroll
    for (int nt = 0; nt < 4; ++nt) c1[d][nt] = (f32x4){0.f, 0.f, 0.f, 0.f};
  {
    bf16x8 aG[3][4];
#pragma unroll
    for (int d = 0; d < 3; ++d)
#pragma unroll
      for (int q = 0; q < 4; ++q)
        aG[d][q] = *(const bf16x8*)(sgA + 128 + d * 128 + quad * 8 + q * 32);
    const ushort_t* W1h = P + 32768;
    const ushort_t* W1l = P + 40960;
#pragma unroll
    for (int nt = 0; nt < 4; ++nt)
#pragma unroll
      for (int q = 0; q < 4; ++q) {
        const int fo = ((nt * 4 + q) * 64 + lane) * 8;
        const bf16x8 bh = *(const bf16x8*)(W1h + fo);
        const bf16x8 bl = *(const bf16x8*)(W1l + fo);
#pragma unroll
        for (int d = 0; d < 3; ++d) {
          c1[d][nt] = __builtin_amdgcn_mfma_f32_16x16x32_bf16(aG[d][q], bh, c1[d][nt], 0, 0, 0);
          c1[d][nt] = __builtin_amdgcn_mfma_f32_16x16x32_bf16(aG[d][q], bl, c1[d][nt], 0, 0, 0);
        }
      }
  }
  // ---- store A1 (out cols 128 + 3m + d) and build B0 in LDS (C- -> A-layout)
#pragma unroll
  for (int d = 0; d < 3; ++d)
#pragma unroll
    for (int nt = 0; nt < 4; ++nt) {
      const int m = nt * 16 + row;
#pragma unroll
      for (int r = 0; r < 4; ++r) {
        const int n = cnode0 + r;
        if (n < n_nodes) out[(size_t)n * ACOLS + HIDDEN + 3 * m + d] = c1[d][nt][r];
      }
    }
#pragma unroll
  for (int nt = 0; nt < 8; ++nt)
#pragma unroll
    for (int r = 0; r < 4; ++r) {
      const float a = c0[nt][r];
      B0s[w][quad * 4 + r][nt * 16 + row] = a * a;
    }
#pragma unroll
  for (int nt = 0; nt < 4; ++nt)
#pragma unroll
    for (int r = 0; r < 4; ++r) {
      const float x = c1[0][nt][r], y = c1[1][nt][r], z = c1[2][nt][r];
      B0s[w][quad * 4 + r][HIDDEN + nt * 16 + row] =
          (x * x + y * y + z * z) * 0.5773502692f;   // /sqrt(3)
    }
  __syncthreads();
  // ---- mix: c0 += B0 @ Wm' (K=192), A split hi/lo in-register (3-term)
  {
    const ushort_t* Wmh = P + 49152;
    const ushort_t* Wml = P + 73728;
#pragma unroll
    for (int q = 0; q < 6; ++q) {
      const float* src = &B0s[w][row][quad * 8 + q * 32];
      bf16x8 ah, al;
#pragma unroll
      for (int j = 0; j < 8; ++j) {
        const float v = src[j];
        const unsigned h = bf16rne(v);
        ah[j] = (short)h;
        al[j] = (short)bf16rne(v - __uint_as_float(h << 16));
      }
#pragma unroll
      for (int nt = 0; nt < 8; ++nt) {
        const int fo = ((nt * 6 + q) * 64 + lane) * 8;
        const bf16x8 bh = *(const bf16x8*)(Wmh + fo);
        const bf16x8 bl = *(const bf16x8*)(Wml + fo);
        c0[nt] = __builtin_amdgcn_mfma_f32_16x16x32_bf16(ah, bh, c0[nt], 0, 0, 0);
        c0[nt] = __builtin_amdgcn_mfma_f32_16x16x32_bf16(al, bh, c0[nt], 0, 0, 0);
        c0[nt] = __builtin_amdgcn_mfma_f32_16x16x32_bf16(ah, bl, c0[nt], 0, 0, 0);
      }
    }
  }
  // ---- store out[:, :128] = A0 + mix0
#pragma unroll
  for (int nt = 0; nt < 8; ++nt)
#pragma unroll
    for (int r = 0; r < 4; ++r) {
      const int n = cnode0 + r;
      if (n < n_nodes) out[(size_t)n * ACOLS + nt * 16 + row] = c0[nt][r];
    }
}

extern "C" void kernel_launch(void* const* d_in, const int* in_sizes, int n_in,
                              void* d_out, int out_size, void* d_ws, size_t ws_size,
                              hipStream_t stream) {
  const float* attrs = (const float*)d_in[0];
  const int*   eidx  = (const int*)d_in[1];
  const float* evec  = (const float*)d_in[2];
  const float* elen  = (const float*)d_in[3];
  const float* W1    = (const float*)d_in[4];
  const float* W2    = (const float*)d_in[5];
  const float* Wtp0  = (const float*)d_in[6];
  const float* Wtp1  = (const float*)d_in[7];
  const float* Wmix  = (const float*)d_in[8];
  float* out = (float*)d_out;

  const int n_nodes = in_sizes[0] / HIDDEN;
  const int n_edges = in_sizes[1] / 2;

  // ws: recs | Tq | cnt | off | cur | SG(1KB/node) | P(192KB)  (~69 MB)
  char* ws = (char*)d_ws;
  float4* recs = (float4*)ws;
  size_t o1 = (((size_t)n_edges * 32) + 255) & ~(size_t)255;
  float* Tq = (float*)(ws + o1);
  size_t o2 = (o1 + (size_t)(TBINS + 1) * HIDDEN * 2 * 4 + 255) & ~(size_t)255;
  int* cnt = (int*)(ws + o2);
  size_t o3 = (o2 + (size_t)n_nodes * 4 + 255) & ~(size_t)255;
  int* off = (int*)(ws + o3);
  size_t o4 = (o3 + (size_t)(n_nodes + 1) * 4 + 255) & ~(size_t)255;
  int* cur = (int*)(ws + o4);
  size_t o5 = (o4 + (size_t)n_nodes * 4 + 255) & ~(size_t)255;
  unsigned* SG = (unsigned*)(ws + o5);
  size_t o6 = o5 + (size_t)n_nodes * 1024;
  ushort_t* P = (ushort_t*)(ws + o6);

  (void)hipMemsetAsync(cnt, 0, (size_t)n_nodes * 4, stream);
  const int hist_blocks = (n_edges + 127) / 128;
  tab_hist<<<TBINS + 1 + hist_blocks, 128, 0, stream>>>(W1, W2, Tq,
                                                        eidx + n_edges, cnt, n_edges);
  scan_kernel<<<1, 1024, 0, stream>>>(cnt, off, cur, n_nodes);
  scatter_kernel<<<(n_edges + 255) / 256, 256, 0, stream>>>(eidx, evec, elen, cur,
                                                            recs, n_edges);
  pack_weights<<<192, 256, 0, stream>>>(Wtp0, Wtp1, Wmix, P);
  node_sg<<<512, 1024, 0, stream>>>(attrs, Tq, recs, off, SG, n_nodes);
  const int ntiles = (n_nodes + 15) / 16;
  node_mfma<<<(ntiles + 3) / 4, 256, 0, stream>>>((const ushort_t*)SG, P, out, n_nodes);
}

// Round 6
// 302.209 us; speedup vs baseline: 4.1982x; 1.3259x over previous
//
#include <hip/hip_runtime.h>
#include <math.h>

#define HIDDEN 128
#define MUL1   64
#define ACOLS  320   // HIDDEN + 3*MUL1
#define TBINS  4096

typedef unsigned short ushort_t;
typedef __attribute__((ext_vector_type(8))) short bf16x8;
typedef __attribute__((ext_vector_type(4))) float f32x4;

__device__ __forceinline__ unsigned bf16rne(float x) {
  const unsigned u = __float_as_uint(x);
  return (u + 0x7FFFu + ((u >> 16) & 1u)) >> 16;
}
__device__ __forceinline__ unsigned pack2(float a, float b) {
  return bf16rne(a) | (bf16rne(b) << 16);
}

// ---------------- K1: fused R_n table build (interleaved pairs) + receiver histogram
__global__ __launch_bounds__(128) void tab_hist(const float* __restrict__ W1,
                                                const float* __restrict__ W2,
                                                float* __restrict__ Tq,
                                                const int* __restrict__ recv,
                                                int* __restrict__ cnt, int n_edges) {
  const int tid = threadIdx.x;
  if (blockIdx.x > TBINS) {   // histogram blocks
    const int e = (blockIdx.x - (TBINS + 1)) * 128 + tid;
    if (e < n_edges) atomicAdd(&cnt[recv[e]], 1);
    return;
  }
  __shared__ float hsh[64];
  const int i = blockIdx.x;        // 0..TBINS
  const float x = (float)i * (5.0f / TBINS);
  if (tid < 64) {
    const bool valid = (x > 0.0f) && (x < 5.0f);
    const float invx = valid ? (1.0f / x) : 0.0f;
    float z = 0.0f;
#pragma unroll
    for (int r = 0; r < 8; ++r) {
      float arg = (float)(r + 1) * 0.6283185307f * x;     // k*pi*x/5
      float rad = 0.6324555320f * sinf(arg) * invx;       // sqrt(2/5)*sin/x
      z += rad * (W1[r * 64 + tid] * 0.3535533906f);      // W1/sqrt(8)
    }
    float sg = 1.0f / (1.0f + expf(-z));
    hsh[tid] = 1.679177f * z * sg;
  }
  __syncthreads();
  float acc = 0.0f;
  for (int j = 0; j < 64; ++j)
    acc += hsh[j] * W2[j * HIDDEN + tid];
  acc *= 0.125f;                                          // W2/8
  Tq[((size_t)i * HIDDEN + tid) * 2] = acc;               // row i as c=0
  if (i >= 1)
    Tq[((size_t)(i - 1) * HIDDEN + tid) * 2 + 1] = acc;   // row i as c=1 of i-1
}

// ---------------- K2a: per-block exclusive scan (1024 elems/block) ----------------
__global__ __launch_bounds__(1024) void scan_blocks(const int* __restrict__ cnt,
                                                    int* __restrict__ partial,
                                                    int* __restrict__ bsums, int n) {
  __shared__ int buf[1024];
  const int t = threadIdx.x;
  const int i = blockIdx.x * 1024 + t;
  const int v = (i < n) ? cnt[i] : 0;
  buf[t] = v;
  __syncthreads();
  for (int d = 1; d < 1024; d <<= 1) {
    const int x = buf[t];
    const int y = (t >= d) ? buf[t - d] : 0;
    __syncthreads();
    buf[t] = x + y;
    __syncthreads();
  }
  if (i < n) partial[i] = buf[t] - v;          // block-local exclusive
  if (t == 1023) bsums[blockIdx.x] = buf[1023];
}

// ---------------- K2b: single-block scan of block sums; writes off[n]=total ------
__global__ __launch_bounds__(1024) void scan_sums(int* __restrict__ bsums, int nb,
                                                  int* __restrict__ off, int n) {
  __shared__ int buf[1024];
  const int t = threadIdx.x;
  const int v = (t < nb) ? bsums[t] : 0;
  buf[t] = v;
  __syncthreads();
  for (int d = 1; d < 1024; d <<= 1) {
    const int x = buf[t];
    const int y = (t >= d) ? buf[t - d] : 0;
    __syncthreads();
    buf[t] = x + y;
    __syncthreads();
  }
  if (t < nb) bsums[t] = buf[t] - v;           // exclusive block offsets
  if (t == nb - 1) off[n] = buf[t];            // grand total
}

// ---------------- K2c: off/cur = partial + block offset ----------------
__global__ __launch_bounds__(256) void scan_final(const int* __restrict__ partial,
                                                  const int* __restrict__ bsums,
                                                  int* __restrict__ off,
                                                  int* __restrict__ cur, int n) {
  const int i = blockIdx.x * 256 + threadIdx.x;
  if (i < n) {
    const int o = partial[i] + bsums[i >> 10];
    off[i] = o;
    cur[i] = o;
  }
}

// ---------------- K3: build sorted 32B edge records ----------------
__global__ void scatter_kernel(const int* __restrict__ eidx,
                               const float* __restrict__ evec,
                               const float* __restrict__ elen,
                               int* __restrict__ cur, float4* __restrict__ recs,
                               int n_edges) {
  const int e = blockIdx.x * blockDim.x + threadIdx.x;
  if (e >= n_edges) return;
  const int s = eidx[e], r = eidx[n_edges + e];
  const float x = elen[e];
  const float v0 = evec[3 * e], v1 = evec[3 * e + 1], v2 = evec[3 * e + 2];
  const float rn = rsqrtf(v0 * v0 + v1 * v1 + v2 * v2);
  const float u = x * ((float)TBINS / 5.0f);
  int i0 = (int)floorf(u);
  i0 = i0 < 0 ? 0 : (i0 > TBINS - 1 ? TBINS - 1 : i0);
  const float fr = u - (float)i0;
  const bool valid = (x > 0.0f) && (x < 5.0f);
  const float w0 = valid ? 1.0f - fr : 0.0f;
  const float w1 = valid ? fr : 0.0f;
  const int pos = atomicAdd(&cur[r], 1);
  recs[2 * pos]     = make_float4(__int_as_float(s), w0, w1, __int_as_float(i0));
  recs[2 * pos + 1] = make_float4(1.7320508076f * v1 * rn,   // unit[:, [1,2,0]]*sqrt3
                                  1.7320508076f * v2 * rn,
                                  1.7320508076f * v0 * rn, 0.0f);
}

// ---------------- K4: pre-scale + hi/lo split weights into MFMA B-frag order ----
// P ushort layout: W0h[16384] W0l[16384] W1h[8192] W1l[8192] Wmh[24576] Wml[24576]
// frag element: P[base + ((nt*KF+q)*64 + lane)*8 + j] = W[(quad*8+j) + q*32][nt*16+col]
__global__ __launch_bounds__(256) void pack_weights(
    const float* __restrict__ W0, const float* __restrict__ W1,
    const float* __restrict__ Wm, ushort_t* __restrict__ P) {
  const int idx = blockIdx.x * 256 + threadIdx.x;     // 0..49151
  const int j = idx & 7, lane = (idx >> 3) & 63;
  const int krow = (lane >> 4) * 8 + j, col = lane & 15;
  float v; int hb, lb;
  if (idx < 16384) {
    const int tq = idx >> 9, nt = tq >> 2, q = tq & 3;
    v = W0[(krow + q * 32) * HIDDEN + nt * 16 + col] * 0.0883883476f;
    hb = idx; lb = idx + 16384;
  } else if (idx < 24576) {
    const int i2 = idx - 16384;
    const int tq = i2 >> 9, nt = tq >> 2, q = tq & 3;
    v = W1[(krow + q * 32) * MUL1 + nt * 16 + col] * 0.0883883476f;
    hb = 32768 + i2; lb = 40960 + i2;
  } else {
    const int i3 = idx - 24576;
    const int tq = i3 >> 9, nt = tq / 6, q = tq % 6;
    v = Wm[(krow + q * 32) * HIDDEN + nt * 16 + col] * 0.0721687836f;
    hb = 49152 + i3; lb = 73728 + i3;
  }
  const unsigned h = bf16rne(v);
  P[hb] = (ushort_t)h;
  P[lb] = (ushort_t)bf16rne(v - __uint_as_float(h << 16));
}

// ---------------- K5: pure gather: per node accumulate S (128) and G (128x3),
// write 1KB bf16 record. No LDS -> high occupancy for latency hiding.
__global__ __launch_bounds__(1024) void node_sg(
    const float* __restrict__ attrs, const float* __restrict__ Tq,
    const float4* __restrict__ recs, const int* __restrict__ off,
    unsigned* __restrict__ SG, int n_nodes) {
  const int lane = threadIdx.x & 63;
  const int wid = (blockIdx.x << 4) + (threadIdx.x >> 6);
  const int nw = gridDim.x << 4;
  const float2* attrs2 = (const float2*)attrs;
  for (int n = wid; n < n_nodes; n += nw) {
    const int beg = off[n], end = off[n + 1];
    float Sa = 0.f, Sb = 0.f;
    float Ga0 = 0.f, Ga1 = 0.f, Ga2 = 0.f, Gb0 = 0.f, Gb1 = 0.f, Gb2 = 0.f;
    for (int i = beg; i < end; i += 2) {
#pragma unroll
      for (int b = 0; b < 2; ++b) {
        const bool ok = (i + b) < end;
        const int idx = ok ? (i + b) : beg;       // clamp; zeroed via weights
        const float4 ra = recs[2 * idx];
        const float4 rb = recs[2 * idx + 1];
        const int s = __float_as_int(ra.x);
        const float w0 = ok ? ra.y : 0.f;
        const float w1v = ok ? ra.z : 0.f;
        const int i0 = __float_as_int(ra.w);
        const float4 tq = *(const float4*)&Tq[((size_t)i0 * HIDDEN + 2 * lane) * 2];
        const float2 av = attrs2[(size_t)s * 64 + lane];
        const float Ra = w0 * tq.x + w1v * tq.y;  // lerp ch 2l
        const float Rb = w0 * tq.z + w1v * tq.w;  // lerp ch 2l+1
        const float la = av.x * Ra, lb = av.y * Rb;
        Sa += la; Sb += lb;
        Ga0 += la * rb.x; Ga1 += la * rb.y; Ga2 += la * rb.z;
        Gb0 += lb * rb.x; Gb1 += lb * rb.y; Gb2 += lb * rb.z;
      }
    }
    unsigned* srow = SG + (size_t)n * 256;        // 256 u32 = 512 bf16 per node
    srow[lane]       = pack2(Sa, Sb);             // S[2l], S[2l+1]
    srow[64 + lane]  = pack2(Ga0, Gb0);           // G_d0
    srow[128 + lane] = pack2(Ga1, Gb1);           // G_d1
    srow[192 + lane] = pack2(Ga2, Gb2);           // G_d2
  }
}

// ---------------- K6: wave-per-16-nodes MFMA: A0=S@W0', A1=G@W1', B0, +=B0@Wm'
// mfma_f32_16x16x32_bf16: A lane: [m=lane&15][k=quad*8+j]; C/D: col=lane&15,
// row=quad*4+reg (m89-verified). Mix GEMM accumulates into A0 C-frags.
__global__ __launch_bounds__(256) void node_mfma(
    const ushort_t* __restrict__ SG, const ushort_t* __restrict__ P,
    float* __restrict__ out, int n_nodes) {
  __shared__ float B0s[4][16][196];   // per-wave B0 stage; stride 196 dw (2-way=free)
  const int lane = threadIdx.x & 63;
  const int w = threadIdx.x >> 6;
  const int tile = blockIdx.x * 4 + w;
  const int row = lane & 15, quad = lane >> 4;
  const int nA = min(tile * 16 + row, n_nodes - 1);   // clamped A-row node
  const ushort_t* sgA = SG + (size_t)nA * 512;
  const int cnode0 = tile * 16 + quad * 4;            // C-frag rows

  // ---- A0 = S @ W0' (M=16 nodes, N=128, K=128), B split hi+lo
  f32x4 c0[8];
#pragma unroll
  for (int nt = 0; nt < 8; ++nt) c0[nt] = (f32x4){0.f, 0.f, 0.f, 0.f};
  {
    bf16x8 aS[4];
#pragma unroll
    for (int q = 0; q < 4; ++q)
      aS[q] = *(const bf16x8*)(sgA + quad * 8 + q * 32);
    const ushort_t* W0h = P;
    const ushort_t* W0l = P + 16384;
#pragma unroll
    for (int nt = 0; nt < 8; ++nt)
#pragma unroll
      for (int q = 0; q < 4; ++q) {
        const int fo = ((nt * 4 + q) * 64 + lane) * 8;
        const bf16x8 bh = *(const bf16x8*)(W0h + fo);
        const bf16x8 bl = *(const bf16x8*)(W0l + fo);
        c0[nt] = __builtin_amdgcn_mfma_f32_16x16x32_bf16(aS[q], bh, c0[nt], 0, 0, 0);
        c0[nt] = __builtin_amdgcn_mfma_f32_16x16x32_bf16(aS[q], bl, c0[nt], 0, 0, 0);
      }
  }
  // ---- A1_d = G_d @ W1' (3 x [M=16, N=64, K=128])
  f32x4 c1[3][4];
#pragma unroll
  for (int d = 0; d < 3; ++d)
#pragma unroll
    for (int nt = 0; nt < 4; ++nt) c1[d][nt] = (f32x4){0.f, 0.f, 0.f, 0.f};
  {
    bf16x8 aG[3][4];
#pragma unroll
    for (int d = 0; d < 3; ++d)
#pragma unroll
      for (int q = 0; q < 4; ++q)
        aG[d][q] = *(const bf16x8*)(sgA + 128 + d * 128 + quad * 8 + q * 32);
    const ushort_t* W1h = P + 32768;
    const ushort_t* W1l = P + 40960;
#pragma unroll
    for (int nt = 0; nt < 4; ++nt)
#pragma unroll
      for (int q = 0; q < 4; ++q) {
        const int fo = ((nt * 4 + q) * 64 + lane) * 8;
        const bf16x8 bh = *(const bf16x8*)(W1h + fo);
        const bf16x8 bl = *(const bf16x8*)(W1l + fo);
#pragma unroll
        for (int d = 0; d < 3; ++d) {
          c1[d][nt] = __builtin_amdgcn_mfma_f32_16x16x32_bf16(aG[d][q], bh, c1[d][nt], 0, 0, 0);
          c1[d][nt] = __builtin_amdgcn_mfma_f32_16x16x32_bf16(aG[d][q], bl, c1[d][nt], 0, 0, 0);
        }
      }
  }
  // ---- store A1 (out cols 128 + 3m + d) and build B0 in LDS (C- -> A-layout)
#pragma unroll
  for (int d = 0; d < 3; ++d)
#pragma unroll
    for (int nt = 0; nt < 4; ++nt) {
      const int m = nt * 16 + row;
#pragma unroll
      for (int r = 0; r < 4; ++r) {
        const int n = cnode0 + r;
        if (n < n_nodes) out[(size_t)n * ACOLS + HIDDEN + 3 * m + d] = c1[d][nt][r];
      }
    }
#pragma unroll
  for (int nt = 0; nt < 8; ++nt)
#pragma unroll
    for (int r = 0; r < 4; ++r) {
      const float a = c0[nt][r];
      B0s[w][quad * 4 + r][nt * 16 + row] = a * a;
    }
#pragma unroll
  for (int nt = 0; nt < 4; ++nt)
#pragma unroll
    for (int r = 0; r < 4; ++r) {
      const float x = c1[0][nt][r], y = c1[1][nt][r], z = c1[2][nt][r];
      B0s[w][quad * 4 + r][HIDDEN + nt * 16 + row] =
          (x * x + y * y + z * z) * 0.5773502692f;   // /sqrt(3)
    }
  __syncthreads();
  // ---- mix: c0 += B0 @ Wm' (K=192), A split hi/lo in-register (3-term)
  {
    const ushort_t* Wmh = P + 49152;
    const ushort_t* Wml = P + 73728;
#pragma unroll
    for (int q = 0; q < 6; ++q) {
      const float* src = &B0s[w][row][quad * 8 + q * 32];
      bf16x8 ah, al;
#pragma unroll
      for (int j = 0; j < 8; ++j) {
        const float v = src[j];
        const unsigned h = bf16rne(v);
        ah[j] = (short)h;
        al[j] = (short)bf16rne(v - __uint_as_float(h << 16));
      }
#pragma unroll
      for (int nt = 0; nt < 8; ++nt) {
        const int fo = ((nt * 6 + q) * 64 + lane) * 8;
        const bf16x8 bh = *(const bf16x8*)(Wmh + fo);
        const bf16x8 bl = *(const bf16x8*)(Wml + fo);
        c0[nt] = __builtin_amdgcn_mfma_f32_16x16x32_bf16(ah, bh, c0[nt], 0, 0, 0);
        c0[nt] = __builtin_amdgcn_mfma_f32_16x16x32_bf16(al, bh, c0[nt], 0, 0, 0);
        c0[nt] = __builtin_amdgcn_mfma_f32_16x16x32_bf16(ah, bl, c0[nt], 0, 0, 0);
      }
    }
  }
  // ---- store out[:, :128] = A0 + mix0
#pragma unroll
  for (int nt = 0; nt < 8; ++nt)
#pragma unroll
    for (int r = 0; r < 4; ++r) {
      const int n = cnode0 + r;
      if (n < n_nodes) out[(size_t)n * ACOLS + nt * 16 + row] = c0[nt][r];
    }
}

extern "C" void kernel_launch(void* const* d_in, const int* in_sizes, int n_in,
                              void* d_out, int out_size, void* d_ws, size_t ws_size,
                              hipStream_t stream) {
  const float* attrs = (const float*)d_in[0];
  const int*   eidx  = (const int*)d_in[1];
  const float* evec  = (const float*)d_in[2];
  const float* elen  = (const float*)d_in[3];
  const float* W1    = (const float*)d_in[4];
  const float* W2    = (const float*)d_in[5];
  const float* Wtp0  = (const float*)d_in[6];
  const float* Wtp1  = (const float*)d_in[7];
  const float* Wmix  = (const float*)d_in[8];
  float* out = (float*)d_out;

  const int n_nodes = in_sizes[0] / HIDDEN;
  const int n_edges = in_sizes[1] / 2;

  // ws: recs | Tq | cnt | off | cur | partial | bsums | SG(1KB/node) | P(192KB)
  char* ws = (char*)d_ws;
  float4* recs = (float4*)ws;
  size_t o1 = (((size_t)n_edges * 32) + 255) & ~(size_t)255;
  float* Tq = (float*)(ws + o1);
  size_t o2 = (o1 + (size_t)(TBINS + 1) * HIDDEN * 2 * 4 + 255) & ~(size_t)255;
  int* cnt = (int*)(ws + o2);
  size_t o3 = (o2 + (size_t)n_nodes * 4 + 255) & ~(size_t)255;
  int* off = (int*)(ws + o3);
  size_t o4 = (o3 + (size_t)(n_nodes + 1) * 4 + 255) & ~(size_t)255;
  int* cur = (int*)(ws + o4);
  size_t o5 = (o4 + (size_t)n_nodes * 4 + 255) & ~(size_t)255;
  int* partial = (int*)(ws + o5);
  size_t o6 = (o5 + (size_t)n_nodes * 4 + 255) & ~(size_t)255;
  int* bsums = (int*)(ws + o6);
  size_t o7 = (o6 + 1024 * 4 + 255) & ~(size_t)255;
  unsigned* SG = (unsigned*)(ws + o7);
  size_t o8 = o7 + (size_t)n_nodes * 1024;
  ushort_t* P = (ushort_t*)(ws + o8);

  (void)hipMemsetAsync(cnt, 0, (size_t)n_nodes * 4, stream);
  const int hist_blocks = (n_edges + 127) / 128;
  tab_hist<<<TBINS + 1 + hist_blocks, 128, 0, stream>>>(W1, W2, Tq,
                                                        eidx + n_edges, cnt, n_edges);
  const int nscan = (n_nodes + 1023) / 1024;
  scan_blocks<<<nscan, 1024, 0, stream>>>(cnt, partial, bsums, n_nodes);
  scan_sums<<<1, 1024, 0, stream>>>(bsums, nscan, off, n_nodes);
  scan_final<<<(n_nodes + 255) / 256, 256, 0, stream>>>(partial, bsums, off, cur,
                                                        n_nodes);
  scatter_kernel<<<(n_edges + 255) / 256, 256, 0, stream>>>(eidx, evec, elen, cur,
                                                            recs, n_edges);
  pack_weights<<<192, 256, 0, stream>>>(Wtp0, Wtp1, Wmix, P);
  node_sg<<<512, 1024, 0, stream>>>(attrs, Tq, recs, off, SG, n_nodes);
  const int ntiles = (n_nodes + 15) / 16;
  node_mfma<<<(ntiles + 3) / 4, 256, 0, stream>>>((const ushort_t*)SG, P, out, n_nodes);
}